// Round 1
// baseline (90.448 us; speedup 1.0000x reference)
//
#include <hip/hip_runtime.h>

#define SEQ   2048
#define HD    64
#define NBH   32
#define QBLK  64
#define KVBLK 64
#define LDK   72            // padded LDS stride (bf16 elems); 144B rows, 16B-aligned
#define NQT   (SEQ / QBLK)  // 32

typedef __attribute__((ext_vector_type(8))) short short8;
typedef __attribute__((ext_vector_type(4))) float floatx4;

static __device__ __forceinline__ short f2bf(float f) {
    union { float f; unsigned u; } x; x.f = f;
    return (short)((x.u + 0x7fffu + ((x.u >> 16) & 1u)) >> 16);  // RNE
}

__global__ __launch_bounds__(256, 2)
void fa_fwd_kernel(const float* __restrict__ Q, const float* __restrict__ K,
                   const float* __restrict__ V, float* __restrict__ O)
{
    const int tid  = threadIdx.x;
    const int lane = tid & 63;
    const int wv   = tid >> 6;        // wave 0..3
    const int l15  = lane & 15;
    const int lg   = lane >> 4;       // 0..3
    const int dofs = lg * 8;          // k-chunk offset within 32-wide MFMA K

    // heavy q-tiles first (qi descending, qi-major) to reduce the causal tail
    const int bh = blockIdx.x & (NBH - 1);
    const int qi = (NQT - 1) - (blockIdx.x >> 5);

    const size_t base = (size_t)bh * SEQ * HD;
    const float* Qp = Q + base;
    const float* Kp = K + base;
    const float* Vp = V + base;
    float*       Op = O + base;
    const int qbase = qi * QBLK;

    __shared__ __align__(16) short K_lds[KVBLK][LDK];
    __shared__ __align__(16) short Vt_lds[HD][LDK];     // V transposed: [d][kv]
    __shared__ __align__(16) short P_lds[4][16][LDK];   // per-wave P tile

    // ---- Q fragments, scale 1/8 folded in ----
    short8 qfrag[2];
    {
        const float* src = Qp + (size_t)(qbase + wv * 16 + l15) * HD + dofs;
        #pragma unroll
        for (int c = 0; c < 2; ++c) {
            float4 f0 = *(const float4*)(src + 32 * c);
            float4 f1 = *(const float4*)(src + 32 * c + 4);
            short8 t;
            t[0] = f2bf(f0.x * 0.125f); t[1] = f2bf(f0.y * 0.125f);
            t[2] = f2bf(f0.z * 0.125f); t[3] = f2bf(f0.w * 0.125f);
            t[4] = f2bf(f1.x * 0.125f); t[5] = f2bf(f1.y * 0.125f);
            t[6] = f2bf(f1.z * 0.125f); t[7] = f2bf(f1.w * 0.125f);
            qfrag[c] = t;
        }
    }

    floatx4 o_acc[4];
    #pragma unroll
    for (int dt = 0; dt < 4; ++dt)
        #pragma unroll
        for (int e = 0; e < 4; ++e) o_acc[dt][e] = 0.0f;
    float m_r[4], l_r[4];
    #pragma unroll
    for (int r = 0; r < 4; ++r) { m_r[r] = -1e30f; l_r[r] = 0.0f; }

    for (int t = 0; t <= qi; ++t) {
        __syncthreads();   // protect LDS from previous iteration's readers
        // ---- stage K (row-major) and V (transposed) as bf16, coalesced ----
        {
            const float4* ks = (const float4*)(Kp + (size_t)t * KVBLK * HD);
            const float4* vs = (const float4*)(Vp + (size_t)t * KVBLK * HD);
            #pragma unroll
            for (int j = 0; j < 4; ++j) {
                int idx = j * 256 + tid;     // float4 index, fully coalesced
                int row = idx >> 4;          // 0..63
                int col = (idx & 15) << 2;   // 0..60
                float4 kf = ks[idx];
                K_lds[row][col + 0] = f2bf(kf.x);
                K_lds[row][col + 1] = f2bf(kf.y);
                K_lds[row][col + 2] = f2bf(kf.z);
                K_lds[row][col + 3] = f2bf(kf.w);
                float4 vf = vs[idx];
                Vt_lds[col + 0][row] = f2bf(vf.x);
                Vt_lds[col + 1][row] = f2bf(vf.y);
                Vt_lds[col + 2][row] = f2bf(vf.z);
                Vt_lds[col + 3][row] = f2bf(vf.w);
            }
        }
        __syncthreads();

        // ---- S = (Q/8) K^T : per wave 16 q-rows x 64 k-cols ----
        floatx4 s_acc[4];
        #pragma unroll
        for (int n = 0; n < 4; ++n) {
            const short8 k0 = *(const short8*)&K_lds[n * 16 + l15][dofs];
            const short8 k1 = *(const short8*)&K_lds[n * 16 + l15][dofs + 32];
            floatx4 acc = {0.0f, 0.0f, 0.0f, 0.0f};
            acc = __builtin_amdgcn_mfma_f32_16x16x32_bf16(qfrag[0], k0, acc, 0, 0, 0);
            acc = __builtin_amdgcn_mfma_f32_16x16x32_bf16(qfrag[1], k1, acc, 0, 0, 0);
            s_acc[n] = acc;
        }

        // ---- causal mask (diagonal tile only) ----
        if (t == qi) {
            #pragma unroll
            for (int n = 0; n < 4; ++n)
                #pragma unroll
                for (int r = 0; r < 4; ++r) {
                    int qr = wv * 16 + lg * 4 + r;   // local q row
                    int kc = n * 16 + l15;           // local k col
                    if (kc > qr) s_acc[n][r] = -1e30f;
                }
        }

        // ---- online softmax (rows live in 16-lane groups) ----
        #pragma unroll
        for (int r = 0; r < 4; ++r) {
            float rmax = fmaxf(fmaxf(s_acc[0][r], s_acc[1][r]),
                               fmaxf(s_acc[2][r], s_acc[3][r]));
            rmax = fmaxf(rmax, __shfl_xor(rmax, 1));
            rmax = fmaxf(rmax, __shfl_xor(rmax, 2));
            rmax = fmaxf(rmax, __shfl_xor(rmax, 4));
            rmax = fmaxf(rmax, __shfl_xor(rmax, 8));
            float mnew  = fmaxf(m_r[r], rmax);
            float alpha = __expf(m_r[r] - mnew);
            m_r[r] = mnew;
            l_r[r] *= alpha;
            #pragma unroll
            for (int dt = 0; dt < 4; ++dt) o_acc[dt][r] *= alpha;
            #pragma unroll
            for (int n = 0; n < 4; ++n) {
                float p = __expf(s_acc[n][r] - mnew);
                l_r[r] += p;
                P_lds[wv][lg * 4 + r][n * 16 + l15] = f2bf(p);
            }
        }
        // wave-local LDS RAW: wait for ds_writes; asm is also a compiler fence
        asm volatile("s_waitcnt lgkmcnt(0)" ::: "memory");

        // ---- O += P V ----
        const short8 p0 = *(const short8*)&P_lds[wv][l15][dofs];
        const short8 p1 = *(const short8*)&P_lds[wv][l15][dofs + 32];
        #pragma unroll
        for (int dt = 0; dt < 4; ++dt) {
            const short8 v0 = *(const short8*)&Vt_lds[dt * 16 + l15][dofs];
            const short8 v1 = *(const short8*)&Vt_lds[dt * 16 + l15][dofs + 32];
            o_acc[dt] = __builtin_amdgcn_mfma_f32_16x16x32_bf16(p0, v0, o_acc[dt], 0, 0, 0);
            o_acc[dt] = __builtin_amdgcn_mfma_f32_16x16x32_bf16(p1, v1, o_acc[dt], 0, 0, 0);
        }
    }

    // ---- finalize: reduce l across the 16-lane group, divide, store ----
    #pragma unroll
    for (int r = 0; r < 4; ++r) {
        float l = l_r[r];
        l += __shfl_xor(l, 1);
        l += __shfl_xor(l, 2);
        l += __shfl_xor(l, 4);
        l += __shfl_xor(l, 8);
        l_r[r] = 1.0f / l;
    }
    #pragma unroll
    for (int dt = 0; dt < 4; ++dt)
        #pragma unroll
        for (int r = 0; r < 4; ++r) {
            int row = qbase + wv * 16 + lg * 4 + r;
            Op[(size_t)row * HD + dt * 16 + l15] = o_acc[dt][r] * l_r[r];
        }
}

extern "C" void kernel_launch(void* const* d_in, const int* in_sizes, int n_in,
                              void* d_out, int out_size, void* d_ws, size_t ws_size,
                              hipStream_t stream) {
    const float* q = (const float*)d_in[0];
    const float* k = (const float*)d_in[1];
    const float* v = (const float*)d_in[2];
    float* o = (float*)d_out;
    (void)in_sizes; (void)n_in; (void)out_size; (void)d_ws; (void)ws_size;
    dim3 grid(NBH * NQT);   // 1024 blocks, qi-major (heavy first)
    dim3 block(256);
    fa_fwd_kernel<<<grid, block, 0, stream>>>(q, k, v, o);
}